// Round 1
// baseline (1297.618 us; speedup 1.0000x reference)
//
#include <hip/hip_runtime.h>

#define NTOK 8192
#define DD 1024
#define HH 4096
#define EE 8

#define BM 128
#define BN 128
#define BK 32
#define PAD 40  // bf16 elems per LDS row (32 + 8 pad, keeps 16B align, breaks bank stride)

typedef __attribute__((ext_vector_type(8))) short bf16x8;
typedef __attribute__((ext_vector_type(4))) float f32x4;

__device__ __forceinline__ unsigned short f2bf(float f) {
  unsigned u = __builtin_bit_cast(unsigned, f);
  u += 0x7fffu + ((u >> 16) & 1u);  // round-to-nearest-even
  return (unsigned short)(u >> 16);
}

union Pack8 {
  unsigned short u[8];
  uint4 v;
};

// ---------------- Router: logits = x*Wr + br; softmax; argmax ----------------
__global__ __launch_bounds__(256) void k_router(
    const float* __restrict__ x, const float* __restrict__ Wr,
    const float* __restrict__ br, float* __restrict__ probs,
    float* __restrict__ idxf, int* __restrict__ idxi) {
  const int lane = threadIdx.x & 63;
  const int token = blockIdx.x * 4 + (threadIdx.x >> 6);
  const float* xr = x + (size_t)token * DD;

  float acc[EE];
#pragma unroll
  for (int e = 0; e < EE; ++e) acc[e] = 0.f;

#pragma unroll
  for (int i = 0; i < 4; ++i) {
    const int d0 = i * 256 + lane * 4;
    const float4 xv = *reinterpret_cast<const float4*>(xr + d0);
    const float xs[4] = {xv.x, xv.y, xv.z, xv.w};
#pragma unroll
    for (int j = 0; j < 4; ++j) {
      const float xd = xs[j];
      const float4 w0 = *reinterpret_cast<const float4*>(Wr + (size_t)(d0 + j) * EE);
      const float4 w1 = *reinterpret_cast<const float4*>(Wr + (size_t)(d0 + j) * EE + 4);
      acc[0] += xd * w0.x; acc[1] += xd * w0.y; acc[2] += xd * w0.z; acc[3] += xd * w0.w;
      acc[4] += xd * w1.x; acc[5] += xd * w1.y; acc[6] += xd * w1.z; acc[7] += xd * w1.w;
    }
  }
  // butterfly reduce across 64 lanes
#pragma unroll
  for (int s = 32; s > 0; s >>= 1) {
#pragma unroll
    for (int e = 0; e < EE; ++e) acc[e] += __shfl_xor(acc[e], s, 64);
  }

  float lg[EE];
#pragma unroll
  for (int e = 0; e < EE; ++e) lg[e] = acc[e] + br[e];

  int best = 0;
  float bv = lg[0];
#pragma unroll
  for (int e = 1; e < EE; ++e) {
    if (lg[e] > bv) { bv = lg[e]; best = e; }  // strict > keeps first-max (numpy tie rule)
  }
  float p[EE], s = 0.f;
#pragma unroll
  for (int e = 0; e < EE; ++e) { p[e] = expf(lg[e] - bv); s += p[e]; }
  const float inv = 1.f / s;

  if (lane == 0) {
#pragma unroll
    for (int e = 0; e < EE; ++e) probs[(size_t)token * EE + e] = p[e] * inv;
    idxf[token] = (float)best;
    idxi[token] = best;
  }
}

// ------------- Stable compaction: counts, offsets, sorted token list -------------
__global__ __launch_bounds__(512) void k_compact(const int* __restrict__ idxi,
                                                 int* __restrict__ cnt,
                                                 int* __restrict__ off,
                                                 int* __restrict__ sorted) {
  __shared__ int sidx[NTOK];
  __shared__ int scnt[EE], soff[EE];
  const int tid = threadIdx.x;
  for (int i = tid; i < NTOK; i += 512) sidx[i] = idxi[i];
  __syncthreads();
  const int w = tid >> 6, lane = tid & 63;
  if (w < EE) {
    int c = 0;
    for (int i = 0; i < NTOK / 64; ++i) {
      unsigned long long m = __ballot(sidx[i * 64 + lane] == w);
      c += __popcll(m);
    }
    if (lane == 0) scnt[w] = c;
  }
  __syncthreads();
  if (tid == 0) {
    int s = 0;
    for (int e = 0; e < EE; ++e) { soff[e] = s; s += scnt[e]; }
  }
  __syncthreads();
  if (w < EE) {
    int base = soff[w];
    const unsigned long long ltmask = (1ull << lane) - 1ull;
    for (int i = 0; i < NTOK / 64; ++i) {
      const int tok = i * 64 + lane;
      const bool f = (sidx[tok] == w);
      unsigned long long m = __ballot(f);
      if (f) {
        int r = __popcll(m & ltmask);
        sorted[base + r] = tok;
      }
      base += __popcll(m);
    }
    if (lane == 0) { cnt[w] = scnt[w]; off[w] = soff[w]; }
  }
}

// ---------------- GEMM1: h = relu(x_sel @ W1[e] + b1[e]) -> bf16 ----------------
__global__ __launch_bounds__(256) void k_gemm1(
    const float* __restrict__ x, const float* __restrict__ W1,
    const float* __restrict__ b1, const int* __restrict__ cnt,
    const int* __restrict__ off, const int* __restrict__ sorted,
    unsigned short* __restrict__ h) {
  const int e = blockIdx.x >> 6;
  const int mb = blockIdx.x & 63;
  const int n0 = blockIdx.y * BN;
  const int c = cnt[e];
  const int m0 = mb * BM;
  if (m0 >= c) return;
  const int base = off[e];

  __shared__ __align__(16) unsigned short Al[BM * PAD];
  __shared__ __align__(16) unsigned short Bl[BN * PAD];

  const int tid = threadIdx.x;
  // A staging: 2 threads per row, 16 floats each
  const int ar = tid >> 1, ah = tid & 1;
  int arow = m0 + ar; if (arow >= c) arow = c - 1;  // clamp: duplicates, masked at write
  const int atok = sorted[base + arow];
  const float* asrc = x + (size_t)atok * DD + ah * 16;
  // B staging: k-strided column loads (coalesced across lanes in n)
  const int bn = tid & 127, bkg = tid >> 7;
  const float* bsrc = W1 + (size_t)e * DD * HH + (size_t)(bkg * 16) * HH + n0 + bn;

  const int lane = tid & 63, w = tid >> 6;
  const int wr = w >> 1, wc = w & 1;
  const int lr = lane & 15, lg = lane >> 4;

  f32x4 acc[4][4];
#pragma unroll
  for (int m = 0; m < 4; ++m)
#pragma unroll
    for (int n = 0; n < 4; ++n) acc[m][n] = {0.f, 0.f, 0.f, 0.f};

  for (int k0 = 0; k0 < DD; k0 += BK) {
    // global loads into regs
    Pack8 pa0, pa1;
    {
      const float* s4 = asrc + k0;
#pragma unroll
      for (int q = 0; q < 2; ++q) {
        float4 f = *reinterpret_cast<const float4*>(s4 + q * 4);
        pa0.u[q * 4 + 0] = f2bf(f.x); pa0.u[q * 4 + 1] = f2bf(f.y);
        pa0.u[q * 4 + 2] = f2bf(f.z); pa0.u[q * 4 + 3] = f2bf(f.w);
      }
#pragma unroll
      for (int q = 0; q < 2; ++q) {
        float4 f = *reinterpret_cast<const float4*>(s4 + 8 + q * 4);
        pa1.u[q * 4 + 0] = f2bf(f.x); pa1.u[q * 4 + 1] = f2bf(f.y);
        pa1.u[q * 4 + 2] = f2bf(f.z); pa1.u[q * 4 + 3] = f2bf(f.w);
      }
    }
    Pack8 pb0, pb1;
    {
      const float* bs = bsrc + (size_t)k0 * HH;
#pragma unroll
      for (int q = 0; q < 8; ++q) pb0.u[q] = f2bf(bs[(size_t)q * HH]);
#pragma unroll
      for (int q = 0; q < 8; ++q) pb1.u[q] = f2bf(bs[(size_t)(q + 8) * HH]);
    }
    __syncthreads();
    *reinterpret_cast<uint4*>(&Al[ar * PAD + ah * 16]) = pa0.v;
    *reinterpret_cast<uint4*>(&Al[ar * PAD + ah * 16 + 8]) = pa1.v;
    *reinterpret_cast<uint4*>(&Bl[bn * PAD + bkg * 16]) = pb0.v;
    *reinterpret_cast<uint4*>(&Bl[bn * PAD + bkg * 16 + 8]) = pb1.v;
    __syncthreads();

    bf16x8 af[4], bf[4];
#pragma unroll
    for (int m = 0; m < 4; ++m)
      af[m] = *reinterpret_cast<const bf16x8*>(&Al[(wr * 64 + m * 16 + lr) * PAD + lg * 8]);
#pragma unroll
    for (int n = 0; n < 4; ++n)
      bf[n] = *reinterpret_cast<const bf16x8*>(&Bl[(wc * 64 + n * 16 + lr) * PAD + lg * 8]);
#pragma unroll
    for (int m = 0; m < 4; ++m)
#pragma unroll
      for (int n = 0; n < 4; ++n)
        acc[m][n] = __builtin_amdgcn_mfma_f32_16x16x32_bf16(af[m], bf[n], acc[m][n], 0, 0, 0);
  }

  const int valid = c - m0;
#pragma unroll
  for (int m = 0; m < 4; ++m) {
#pragma unroll
    for (int r = 0; r < 4; ++r) {
      const int tr = wr * 64 + m * 16 + lg * 4 + r;
      if (tr < valid) {
        const size_t row = (size_t)(base + m0 + tr);
#pragma unroll
        for (int n = 0; n < 4; ++n) {
          const int col = n0 + wc * 64 + n * 16 + lr;
          float v = acc[m][n][r] + b1[e * HH + col];
          v = fmaxf(v, 0.f);
          h[row * HH + col] = f2bf(v);
        }
      }
    }
  }
}

// ---------------- GEMM2: out[token] = h @ W2[e] + b2[e] (scatter) ----------------
__global__ __launch_bounds__(256) void k_gemm2(
    const unsigned short* __restrict__ h, const float* __restrict__ W2,
    const float* __restrict__ b2, const int* __restrict__ cnt,
    const int* __restrict__ off, const int* __restrict__ sorted,
    float* __restrict__ out) {
  const int e = blockIdx.x >> 6;
  const int mb = blockIdx.x & 63;
  const int n0 = blockIdx.y * BN;
  const int c = cnt[e];
  const int m0 = mb * BM;
  if (m0 >= c) return;
  const int base = off[e];

  __shared__ __align__(16) unsigned short Al[BM * PAD];
  __shared__ __align__(16) unsigned short Bl[BN * PAD];

  const int tid = threadIdx.x;
  const int ar = tid >> 1, ah = tid & 1;
  int arow = m0 + ar; if (arow >= c) arow = c - 1;
  const unsigned short* asrc = h + (size_t)(base + arow) * HH + ah * 16;
  const int bn = tid & 127, bkg = tid >> 7;
  const float* bsrc = W2 + (size_t)e * HH * DD + (size_t)(bkg * 16) * DD + n0 + bn;

  const int lane = tid & 63, w = tid >> 6;
  const int wr = w >> 1, wc = w & 1;
  const int lr = lane & 15, lg = lane >> 4;

  f32x4 acc[4][4];
#pragma unroll
  for (int m = 0; m < 4; ++m)
#pragma unroll
    for (int n = 0; n < 4; ++n) acc[m][n] = {0.f, 0.f, 0.f, 0.f};

  for (int k0 = 0; k0 < HH; k0 += BK) {
    const uint4 a0 = *reinterpret_cast<const uint4*>(asrc + k0);
    const uint4 a1 = *reinterpret_cast<const uint4*>(asrc + k0 + 8);
    Pack8 pb0, pb1;
    {
      const float* bs = bsrc + (size_t)k0 * DD;
#pragma unroll
      for (int q = 0; q < 8; ++q) pb0.u[q] = f2bf(bs[(size_t)q * DD]);
#pragma unroll
      for (int q = 0; q < 8; ++q) pb1.u[q] = f2bf(bs[(size_t)(q + 8) * DD]);
    }
    __syncthreads();
    *reinterpret_cast<uint4*>(&Al[ar * PAD + ah * 16]) = a0;
    *reinterpret_cast<uint4*>(&Al[ar * PAD + ah * 16 + 8]) = a1;
    *reinterpret_cast<uint4*>(&Bl[bn * PAD + bkg * 16]) = pb0.v;
    *reinterpret_cast<uint4*>(&Bl[bn * PAD + bkg * 16 + 8]) = pb1.v;
    __syncthreads();

    bf16x8 af[4], bf[4];
#pragma unroll
    for (int m = 0; m < 4; ++m)
      af[m] = *reinterpret_cast<const bf16x8*>(&Al[(wr * 64 + m * 16 + lr) * PAD + lg * 8]);
#pragma unroll
    for (int n = 0; n < 4; ++n)
      bf[n] = *reinterpret_cast<const bf16x8*>(&Bl[(wc * 64 + n * 16 + lr) * PAD + lg * 8]);
#pragma unroll
    for (int m = 0; m < 4; ++m)
#pragma unroll
      for (int n = 0; n < 4; ++n)
        acc[m][n] = __builtin_amdgcn_mfma_f32_16x16x32_bf16(af[m], bf[n], acc[m][n], 0, 0, 0);
  }

  const int valid = c - m0;
#pragma unroll
  for (int m = 0; m < 4; ++m) {
#pragma unroll
    for (int r = 0; r < 4; ++r) {
      const int tr = wr * 64 + m * 16 + lg * 4 + r;
      if (tr < valid) {
        const int token = sorted[base + m0 + tr];
#pragma unroll
        for (int n = 0; n < 4; ++n) {
          const int col = n0 + wc * 64 + n * 16 + lr;
          out[(size_t)token * DD + col] = acc[m][n][r] + b2[e * DD + col];
        }
      }
    }
  }
}

extern "C" void kernel_launch(void* const* d_in, const int* in_sizes, int n_in,
                              void* d_out, int out_size, void* d_ws, size_t ws_size,
                              hipStream_t stream) {
  const float* x  = (const float*)d_in[0];
  const float* Wr = (const float*)d_in[1];
  const float* br = (const float*)d_in[2];
  const float* W1 = (const float*)d_in[3];
  const float* b1 = (const float*)d_in[4];
  const float* W2 = (const float*)d_in[5];
  const float* b2 = (const float*)d_in[6];

  float* out   = (float*)d_out;
  float* probs = out + (size_t)NTOK * DD;            // 8,388,608
  float* idxf  = probs + (size_t)NTOK * EE;          // +65,536

  char* ws = (char*)d_ws;
  int* cnt    = (int*)(ws);
  int* off    = (int*)(ws + 64);
  int* idxi   = (int*)(ws + 128);
  int* sorted = (int*)(ws + 128 + NTOK * 4);
  unsigned short* h = (unsigned short*)(ws + 128 + 2 * NTOK * 4);  // 64 MB bf16 [NTOK][HH]

  k_router<<<NTOK / 4, 256, 0, stream>>>(x, Wr, br, probs, idxf, idxi);
  k_compact<<<1, 512, 0, stream>>>(idxi, cnt, off, sorted);
  k_gemm1<<<dim3(EE * (NTOK / BM), HH / BN), 256, 0, stream>>>(x, W1, b1, cnt, off, sorted, h);
  k_gemm2<<<dim3(EE * (NTOK / BM), DD / BN), 256, 0, stream>>>(h, W2, b2, cnt, off, sorted, out);
}

// Round 2
// 400.660 us; speedup vs baseline: 3.2387x; 3.2387x over previous
//
#include <hip/hip_runtime.h>

#define NTOK 8192
#define DD 1024
#define HH 4096
#define EE 8
#define MAXBLK 72

typedef __attribute__((ext_vector_type(8))) short bf16x8;
typedef __attribute__((ext_vector_type(4))) float f32x4;

__device__ __forceinline__ unsigned short f2bf(float f) {
  unsigned u = __builtin_bit_cast(unsigned, f);
  u += 0x7fffu + ((u >> 16) & 1u);  // round-to-nearest-even
  return (unsigned short)(u >> 16);
}

union Pack8 {
  unsigned short u[8];
  uint4 v;
};

__device__ __forceinline__ void gload_lds16(const void* g, void* l) {
  __builtin_amdgcn_global_load_lds(
      (const __attribute__((address_space(1))) unsigned int*)g,
      (__attribute__((address_space(3))) unsigned int*)l, 16, 0, 0);
}

// ---------------- Router: logits = x*Wr + br; softmax; argmax ----------------
__global__ __launch_bounds__(256) void k_router(
    const float* __restrict__ x, const float* __restrict__ Wr,
    const float* __restrict__ br, float* __restrict__ probs,
    float* __restrict__ idxf, int* __restrict__ idxi) {
  const int lane = threadIdx.x & 63;
  const int token = blockIdx.x * 4 + (threadIdx.x >> 6);
  const float* xr = x + (size_t)token * DD;

  float acc[EE];
#pragma unroll
  for (int e = 0; e < EE; ++e) acc[e] = 0.f;

#pragma unroll
  for (int i = 0; i < 4; ++i) {
    const int d0 = i * 256 + lane * 4;
    const float4 xv = *reinterpret_cast<const float4*>(xr + d0);
    const float xs[4] = {xv.x, xv.y, xv.z, xv.w};
#pragma unroll
    for (int j = 0; j < 4; ++j) {
      const float xd = xs[j];
      const float4 w0 = *reinterpret_cast<const float4*>(Wr + (size_t)(d0 + j) * EE);
      const float4 w1 = *reinterpret_cast<const float4*>(Wr + (size_t)(d0 + j) * EE + 4);
      acc[0] += xd * w0.x; acc[1] += xd * w0.y; acc[2] += xd * w0.z; acc[3] += xd * w0.w;
      acc[4] += xd * w1.x; acc[5] += xd * w1.y; acc[6] += xd * w1.z; acc[7] += xd * w1.w;
    }
  }
#pragma unroll
  for (int s = 32; s > 0; s >>= 1) {
#pragma unroll
    for (int e = 0; e < EE; ++e) acc[e] += __shfl_xor(acc[e], s, 64);
  }

  float lg[EE];
#pragma unroll
  for (int e = 0; e < EE; ++e) lg[e] = acc[e] + br[e];

  int best = 0;
  float bv = lg[0];
#pragma unroll
  for (int e = 1; e < EE; ++e) {
    if (lg[e] > bv) { bv = lg[e]; best = e; }
  }
  float p[EE], s = 0.f;
#pragma unroll
  for (int e = 0; e < EE; ++e) { p[e] = expf(lg[e] - bv); s += p[e]; }
  const float inv = 1.f / s;

  if (lane == 0) {
#pragma unroll
    for (int e = 0; e < EE; ++e) probs[(size_t)token * EE + e] = p[e] * inv;
    idxf[token] = (float)best;
    idxi[token] = best;
  }
}

// ------------- Stable compaction + block table -------------
__global__ __launch_bounds__(512) void k_compact(const int* __restrict__ idxi,
                                                 int* __restrict__ cnt,
                                                 int* __restrict__ off,
                                                 int* __restrict__ sorted,
                                                 int* __restrict__ meta) {
  __shared__ int sidx[NTOK];
  __shared__ int scnt[EE], soff[EE];
  const int tid = threadIdx.x;
  for (int i = tid; i < NTOK; i += 512) sidx[i] = idxi[i];
  __syncthreads();
  const int w = tid >> 6, lane = tid & 63;
  if (w < EE) {
    int c = 0;
    for (int i = 0; i < NTOK / 64; ++i) {
      unsigned long long m = __ballot(sidx[i * 64 + lane] == w);
      c += __popcll(m);
    }
    if (lane == 0) scnt[w] = c;
  }
  __syncthreads();
  if (tid == 0) {
    int s = 0;
    for (int e = 0; e < EE; ++e) { soff[e] = s; s += scnt[e]; }
    int nb = 0;
    for (int e = 0; e < EE; ++e) {
      const int nmb = (scnt[e] + 127) >> 7;
      for (int m = 0; m < nmb; ++m) {
        meta[16 + nb] = e;        // blk_e
        meta[96 + nb] = m << 7;   // blk_m0
        ++nb;
      }
    }
    meta[0] = nb;
  }
  __syncthreads();
  if (w < EE) {
    int base = soff[w];
    const unsigned long long ltmask = (1ull << lane) - 1ull;
    for (int i = 0; i < NTOK / 64; ++i) {
      const int tok = i * 64 + lane;
      const bool f = (sidx[tok] == w);
      unsigned long long m = __ballot(f);
      if (f) {
        int r = __popcll(m & ltmask);
        sorted[base + r] = tok;
      }
      base += __popcll(m);
    }
    if (lane == 0) { cnt[w] = scnt[w]; off[w] = soff[w]; }
  }
}

// ---------------- x f32 -> bf16 ----------------
__global__ __launch_bounds__(256) void k_cvt_x(const float* __restrict__ x,
                                               unsigned short* __restrict__ xb) {
  const size_t i = ((size_t)blockIdx.x * 256 + threadIdx.x) * 8;
  const float4 a = *reinterpret_cast<const float4*>(x + i);
  const float4 b = *reinterpret_cast<const float4*>(x + i + 4);
  Pack8 p;
  p.u[0] = f2bf(a.x); p.u[1] = f2bf(a.y); p.u[2] = f2bf(a.z); p.u[3] = f2bf(a.w);
  p.u[4] = f2bf(b.x); p.u[5] = f2bf(b.y); p.u[6] = f2bf(b.z); p.u[7] = f2bf(b.w);
  *reinterpret_cast<uint4*>(xb + i) = p.v;
}

// ---------------- transpose+convert: in [E][R][C] f32 -> out [E][C][R] bf16 ----------------
__global__ __launch_bounds__(256) void k_trcvt(const float* __restrict__ in,
                                               unsigned short* __restrict__ outp,
                                               int R, int C) {
  const int e = blockIdx.z;
  const float* src = in + (size_t)e * R * C;
  unsigned short* dst = outp + (size_t)e * R * C;
  __shared__ float t[32][33];
  const int r0 = blockIdx.y * 32, c0 = blockIdx.x * 32;
  const int tr = threadIdx.x >> 3, tc4 = (threadIdx.x & 7) * 4;
  const float4 v = *reinterpret_cast<const float4*>(src + (size_t)(r0 + tr) * C + c0 + tc4);
  t[tr][tc4 + 0] = v.x; t[tr][tc4 + 1] = v.y; t[tr][tc4 + 2] = v.z; t[tr][tc4 + 3] = v.w;
  __syncthreads();
  union { unsigned short u[4]; uint2 v2; } p;
#pragma unroll
  for (int j = 0; j < 4; ++j) p.u[j] = f2bf(t[tc4 + j][tr]);
  *reinterpret_cast<uint2*>(&dst[(size_t)(c0 + tr) * R + r0 + tc4]) = p.v2;
}

// ---------------- GEMM1: h = relu(xb_sel @ W1t^T + b1) -> bf16 ----------------
// A = gathered xb rows [128][K=1024], B = W1t rows (n-major) [128][K], 128x128 tile, BK=64
__global__ __launch_bounds__(256) void k_gemm1n(
    const unsigned short* __restrict__ xb, const unsigned short* __restrict__ W1t,
    const float* __restrict__ b1, const int* __restrict__ meta,
    const int* __restrict__ cnt, const int* __restrict__ off,
    const int* __restrict__ sorted, unsigned short* __restrict__ h) {
  const int bid = blockIdx.x;
  if (bid >= meta[0]) return;
  const int e = meta[16 + bid];
  const int m0 = meta[96 + bid];
  const int c = cnt[e], base = off[e];
  const int n0 = blockIdx.y * 128;

  __shared__ __align__(16) unsigned short Al[128 * 64];
  __shared__ __align__(16) unsigned short Bl[128 * 64];

  const int tid = threadIdx.x, l = tid & 63, w = tid >> 6;

  const unsigned short* aptr[4];
  const unsigned short* bptr[4];
  unsigned short* alds[4];
  unsigned short* blds[4];
#pragma unroll
  for (int i = 0; i < 4; ++i) {
    const int r = i * 32 + w * 8 + (l >> 3);
    const int swz = ((l & 7) ^ (r & 7)) * 8;  // pre-swizzled global source (m173)
    int ar = m0 + r; if (ar >= c) ar = c - 1;
    const int tok = sorted[base + ar];
    aptr[i] = xb + (size_t)tok * DD + swz;
    bptr[i] = W1t + ((size_t)e * HH + n0 + r) * DD + swz;
    alds[i] = &Al[r * 64 + (l & 7) * 8];
    blds[i] = &Bl[r * 64 + (l & 7) * 8];
  }

  const int lr = l & 15, lg = l >> 4;
  const int wr = w >> 1, wc = w & 1;
  int aoff[4], bofr[4], aswz[4], bswz[4];
#pragma unroll
  for (int m = 0; m < 4; ++m) {
    int row = wr * 64 + m * 16 + lr;
    aoff[m] = row * 64; aswz[m] = row & 7;
    row = wc * 64 + m * 16 + lr;
    bofr[m] = row * 64; bswz[m] = row & 7;
  }

  f32x4 acc[4][4];
#pragma unroll
  for (int m = 0; m < 4; ++m)
#pragma unroll
    for (int n = 0; n < 4; ++n) acc[m][n] = {0.f, 0.f, 0.f, 0.f};

  for (int k0 = 0; k0 < DD; k0 += 64) {
    __syncthreads();
#pragma unroll
    for (int i = 0; i < 4; ++i) gload_lds16(aptr[i] + k0, alds[i]);
#pragma unroll
    for (int i = 0; i < 4; ++i) gload_lds16(bptr[i] + k0, blds[i]);
    __syncthreads();
#pragma unroll
    for (int ks = 0; ks < 2; ++ks) {
      bf16x8 af[4], bv[4];
#pragma unroll
      for (int m = 0; m < 4; ++m)
        af[m] = *reinterpret_cast<const bf16x8*>(&Al[aoff[m] + (((ks * 4 + lg) ^ aswz[m]) * 8)]);
#pragma unroll
      for (int n = 0; n < 4; ++n)
        bv[n] = *reinterpret_cast<const bf16x8*>(&Bl[bofr[n] + (((ks * 4 + lg) ^ bswz[n]) * 8)]);
#pragma unroll
      for (int m = 0; m < 4; ++m)
#pragma unroll
        for (int n = 0; n < 4; ++n)
          acc[m][n] = __builtin_amdgcn_mfma_f32_16x16x32_bf16(af[m], bv[n], acc[m][n], 0, 0, 0);
    }
  }

  const int valid = c - m0;
#pragma unroll
  for (int m = 0; m < 4; ++m) {
#pragma unroll
    for (int rr = 0; rr < 4; ++rr) {
      const int tr = wr * 64 + m * 16 + lg * 4 + rr;
      if (tr < valid) {
        const size_t row = (size_t)(base + m0 + tr);
#pragma unroll
        for (int n = 0; n < 4; ++n) {
          const int col = n0 + wc * 64 + n * 16 + lr;
          const float v = acc[m][n][rr] + b1[e * HH + col];
          h[row * HH + col] = f2bf(fmaxf(v, 0.f));
        }
      }
    }
  }
}

// ---------------- GEMM2: out[token] = h @ W2t^T + b2 (scatter, f32) ----------------
__global__ __launch_bounds__(256) void k_gemm2n(
    const unsigned short* __restrict__ h, const unsigned short* __restrict__ W2t,
    const float* __restrict__ b2, const int* __restrict__ meta,
    const int* __restrict__ cnt, const int* __restrict__ off,
    const int* __restrict__ sorted, float* __restrict__ out) {
  const int bid = blockIdx.x;
  if (bid >= meta[0]) return;
  const int e = meta[16 + bid];
  const int m0 = meta[96 + bid];
  const int c = cnt[e], base = off[e];
  const int n0 = blockIdx.y * 128;

  __shared__ __align__(16) unsigned short Al[128 * 64];
  __shared__ __align__(16) unsigned short Bl[128 * 64];

  const int tid = threadIdx.x, l = tid & 63, w = tid >> 6;

  const unsigned short* aptr[4];
  const unsigned short* bptr[4];
  unsigned short* alds[4];
  unsigned short* blds[4];
#pragma unroll
  for (int i = 0; i < 4; ++i) {
    const int r = i * 32 + w * 8 + (l >> 3);
    const int swz = ((l & 7) ^ (r & 7)) * 8;
    int ar = m0 + r; if (ar >= c) ar = c - 1;
    aptr[i] = h + (size_t)(base + ar) * HH + swz;
    bptr[i] = W2t + ((size_t)e * DD + n0 + r) * HH + swz;
    alds[i] = &Al[r * 64 + (l & 7) * 8];
    blds[i] = &Bl[r * 64 + (l & 7) * 8];
  }

  const int lr = l & 15, lg = l >> 4;
  const int wr = w >> 1, wc = w & 1;
  int aoff[4], bofr[4], aswz[4], bswz[4];
#pragma unroll
  for (int m = 0; m < 4; ++m) {
    int row = wr * 64 + m * 16 + lr;
    aoff[m] = row * 64; aswz[m] = row & 7;
    row = wc * 64 + m * 16 + lr;
    bofr[m] = row * 64; bswz[m] = row & 7;
  }

  f32x4 acc[4][4];
#pragma unroll
  for (int m = 0; m < 4; ++m)
#pragma unroll
    for (int n = 0; n < 4; ++n) acc[m][n] = {0.f, 0.f, 0.f, 0.f};

  for (int k0 = 0; k0 < HH; k0 += 64) {
    __syncthreads();
#pragma unroll
    for (int i = 0; i < 4; ++i) gload_lds16(aptr[i] + k0, alds[i]);
#pragma unroll
    for (int i = 0; i < 4; ++i) gload_lds16(bptr[i] + k0, blds[i]);
    __syncthreads();
#pragma unroll
    for (int ks = 0; ks < 2; ++ks) {
      bf16x8 af[4], bv[4];
#pragma unroll
      for (int m = 0; m < 4; ++m)
        af[m] = *reinterpret_cast<const bf16x8*>(&Al[aoff[m] + (((ks * 4 + lg) ^ aswz[m]) * 8)]);
#pragma unroll
      for (int n = 0; n < 4; ++n)
        bv[n] = *reinterpret_cast<const bf16x8*>(&Bl[bofr[n] + (((ks * 4 + lg) ^ bswz[n]) * 8)]);
#pragma unroll
      for (int m = 0; m < 4; ++m)
#pragma unroll
        for (int n = 0; n < 4; ++n)
          acc[m][n] = __builtin_amdgcn_mfma_f32_16x16x32_bf16(af[m], bv[n], acc[m][n], 0, 0, 0);
    }
  }

  const int valid = c - m0;
#pragma unroll
  for (int m = 0; m < 4; ++m) {
#pragma unroll
    for (int rr = 0; rr < 4; ++rr) {
      const int tr = wr * 64 + m * 16 + lg * 4 + rr;
      if (tr < valid) {
        const int token = sorted[base + m0 + tr];
#pragma unroll
        for (int n = 0; n < 4; ++n) {
          const int col = n0 + wc * 64 + n * 16 + lr;
          out[(size_t)token * DD + col] = acc[m][n][rr] + b2[e * DD + col];
        }
      }
    }
  }
}

// ================= Fallback (round-1) kernels: f32 reg-staged GEMMs =================
#define BM 128
#define BN 128
#define BK 32
#define PAD 40

__global__ __launch_bounds__(256) void k_gemm1_f32(
    const float* __restrict__ x, const float* __restrict__ W1,
    const float* __restrict__ b1, const int* __restrict__ cnt,
    const int* __restrict__ off, const int* __restrict__ sorted,
    unsigned short* __restrict__ h) {
  const int e = blockIdx.x >> 6;
  const int mb = blockIdx.x & 63;
  const int n0 = blockIdx.y * BN;
  const int c = cnt[e];
  const int m0 = mb * BM;
  if (m0 >= c) return;
  const int base = off[e];

  __shared__ __align__(16) unsigned short Al[BM * PAD];
  __shared__ __align__(16) unsigned short Bl[BN * PAD];

  const int tid = threadIdx.x;
  const int ar = tid >> 1, ah = tid & 1;
  int arow = m0 + ar; if (arow >= c) arow = c - 1;
  const int atok = sorted[base + arow];
  const float* asrc = x + (size_t)atok * DD + ah * 16;
  const int bn = tid & 127, bkg = tid >> 7;
  const float* bsrc = W1 + (size_t)e * DD * HH + (size_t)(bkg * 16) * HH + n0 + bn;

  const int lane = tid & 63, w = tid >> 6;
  const int wr = w >> 1, wc = w & 1;
  const int lr = lane & 15, lg = lane >> 4;

  f32x4 acc[4][4];
#pragma unroll
  for (int m = 0; m < 4; ++m)
#pragma unroll
    for (int n = 0; n < 4; ++n) acc[m][n] = {0.f, 0.f, 0.f, 0.f};

  for (int k0 = 0; k0 < DD; k0 += BK) {
    Pack8 pa0, pa1;
    {
      const float* s4 = asrc + k0;
#pragma unroll
      for (int q = 0; q < 2; ++q) {
        float4 f = *reinterpret_cast<const float4*>(s4 + q * 4);
        pa0.u[q * 4 + 0] = f2bf(f.x); pa0.u[q * 4 + 1] = f2bf(f.y);
        pa0.u[q * 4 + 2] = f2bf(f.z); pa0.u[q * 4 + 3] = f2bf(f.w);
      }
#pragma unroll
      for (int q = 0; q < 2; ++q) {
        float4 f = *reinterpret_cast<const float4*>(s4 + 8 + q * 4);
        pa1.u[q * 4 + 0] = f2bf(f.x); pa1.u[q * 4 + 1] = f2bf(f.y);
        pa1.u[q * 4 + 2] = f2bf(f.z); pa1.u[q * 4 + 3] = f2bf(f.w);
      }
    }
    Pack8 pb0, pb1;
    {
      const float* bs = bsrc + (size_t)k0 * HH;
#pragma unroll
      for (int q = 0; q < 8; ++q) pb0.u[q] = f2bf(bs[(size_t)q * HH]);
#pragma unroll
      for (int q = 0; q < 8; ++q) pb1.u[q] = f2bf(bs[(size_t)(q + 8) * HH]);
    }
    __syncthreads();
    *reinterpret_cast<uint4*>(&Al[ar * PAD + ah * 16]) = pa0.v;
    *reinterpret_cast<uint4*>(&Al[ar * PAD + ah * 16 + 8]) = pa1.v;
    *reinterpret_cast<uint4*>(&Bl[bn * PAD + bkg * 16]) = pb0.v;
    *reinterpret_cast<uint4*>(&Bl[bn * PAD + bkg * 16 + 8]) = pb1.v;
    __syncthreads();

    bf16x8 af[4], bf[4];
#pragma unroll
    for (int m = 0; m < 4; ++m)
      af[m] = *reinterpret_cast<const bf16x8*>(&Al[(wr * 64 + m * 16 + lr) * PAD + lg * 8]);
#pragma unroll
    for (int n = 0; n < 4; ++n)
      bf[n] = *reinterpret_cast<const bf16x8*>(&Bl[(wc * 64 + n * 16 + lr) * PAD + lg * 8]);
#pragma unroll
    for (int m = 0; m < 4; ++m)
#pragma unroll
      for (int n = 0; n < 4; ++n)
        acc[m][n] = __builtin_amdgcn_mfma_f32_16x16x32_bf16(af[m], bf[n], acc[m][n], 0, 0, 0);
  }

  const int valid = c - m0;
#pragma unroll
  for (int m = 0; m < 4; ++m) {
#pragma unroll
    for (int r = 0; r < 4; ++r) {
      const int tr = wr * 64 + m * 16 + lg * 4 + r;
      if (tr < valid) {
        const size_t row = (size_t)(base + m0 + tr);
#pragma unroll
        for (int n = 0; n < 4; ++n) {
          const int col = n0 + wc * 64 + n * 16 + lr;
          float v = acc[m][n][r] + b1[e * HH + col];
          v = fmaxf(v, 0.f);
          h[row * HH + col] = f2bf(v);
        }
      }
    }
  }
}

__global__ __launch_bounds__(256) void k_gemm2_f32(
    const unsigned short* __restrict__ h, const float* __restrict__ W2,
    const float* __restrict__ b2, const int* __restrict__ cnt,
    const int* __restrict__ off, const int* __restrict__ sorted,
    float* __restrict__ out) {
  const int e = blockIdx.x >> 6;
  const int mb = blockIdx.x & 63;
  const int n0 = blockIdx.y * BN;
  const int c = cnt[e];
  const int m0 = mb * BM;
  if (m0 >= c) return;
  const int base = off[e];

  __shared__ __align__(16) unsigned short Al[BM * PAD];
  __shared__ __align__(16) unsigned short Bl[BN * PAD];

  const int tid = threadIdx.x;
  const int ar = tid >> 1, ah = tid & 1;
  int arow = m0 + ar; if (arow >= c) arow = c - 1;
  const unsigned short* asrc = h + (size_t)(base + arow) * HH + ah * 16;
  const int bn = tid & 127, bkg = tid >> 7;
  const float* bsrc = W2 + (size_t)e * HH * DD + (size_t)(bkg * 16) * DD + n0 + bn;

  const int lane = tid & 63, w = tid >> 6;
  const int wr = w >> 1, wc = w & 1;
  const int lr = lane & 15, lg = lane >> 4;

  f32x4 acc[4][4];
#pragma unroll
  for (int m = 0; m < 4; ++m)
#pragma unroll
    for (int n = 0; n < 4; ++n) acc[m][n] = {0.f, 0.f, 0.f, 0.f};

  for (int k0 = 0; k0 < HH; k0 += BK) {
    const uint4 a0 = *reinterpret_cast<const uint4*>(asrc + k0);
    const uint4 a1 = *reinterpret_cast<const uint4*>(asrc + k0 + 8);
    Pack8 pb0, pb1;
    {
      const float* bs = bsrc + (size_t)k0 * DD;
#pragma unroll
      for (int q = 0; q < 8; ++q) pb0.u[q] = f2bf(bs[(size_t)q * DD]);
#pragma unroll
      for (int q = 0; q < 8; ++q) pb1.u[q] = f2bf(bs[(size_t)(q + 8) * DD]);
    }
    __syncthreads();
    *reinterpret_cast<uint4*>(&Al[ar * PAD + ah * 16]) = a0;
    *reinterpret_cast<uint4*>(&Al[ar * PAD + ah * 16 + 8]) = a1;
    *reinterpret_cast<uint4*>(&Bl[bn * PAD + bkg * 16]) = pb0.v;
    *reinterpret_cast<uint4*>(&Bl[bn * PAD + bkg * 16 + 8]) = pb1.v;
    __syncthreads();

    bf16x8 af[4], bf[4];
#pragma unroll
    for (int m = 0; m < 4; ++m)
      af[m] = *reinterpret_cast<const bf16x8*>(&Al[(wr * 64 + m * 16 + lr) * PAD + lg * 8]);
#pragma unroll
    for (int n = 0; n < 4; ++n)
      bf[n] = *reinterpret_cast<const bf16x8*>(&Bl[(wc * 64 + n * 16 + lr) * PAD + lg * 8]);
#pragma unroll
    for (int m = 0; m < 4; ++m)
#pragma unroll
      for (int n = 0; n < 4; ++n)
        acc[m][n] = __builtin_amdgcn_mfma_f32_16x16x32_bf16(af[m], bf[n], acc[m][n], 0, 0, 0);
  }

  const int valid = c - m0;
#pragma unroll
  for (int m = 0; m < 4; ++m) {
#pragma unroll
    for (int r = 0; r < 4; ++r) {
      const int tr = wr * 64 + m * 16 + lg * 4 + r;
      if (tr < valid) {
        const int token = sorted[base + m0 + tr];
#pragma unroll
        for (int n = 0; n < 4; ++n) {
          const int col = n0 + wc * 64 + n * 16 + lr;
          out[(size_t)token * DD + col] = acc[m][n][r] + b2[e * DD + col];
        }
      }
    }
  }
}

extern "C" void kernel_launch(void* const* d_in, const int* in_sizes, int n_in,
                              void* d_out, int out_size, void* d_ws, size_t ws_size,
                              hipStream_t stream) {
  const float* x  = (const float*)d_in[0];
  const float* Wr = (const float*)d_in[1];
  const float* br = (const float*)d_in[2];
  const float* W1 = (const float*)d_in[3];
  const float* b1 = (const float*)d_in[4];
  const float* W2 = (const float*)d_in[5];
  const float* b2 = (const float*)d_in[6];

  float* out   = (float*)d_out;
  float* probs = out + (size_t)NTOK * DD;
  float* idxf  = probs + (size_t)NTOK * EE;

  char* ws = (char*)d_ws;
  int* cnt    = (int*)(ws + 0);
  int* off    = (int*)(ws + 64);
  int* meta   = (int*)(ws + 128);      // [0]=nblk, [16..]=blk_e, [96..]=blk_m0
  int* idxi   = (int*)(ws + 1024);
  int* sorted = (int*)(ws + 33792);

  const size_t OFF_XB  = 66560;                       // 16 MB
  const size_t OFF_W1T = OFF_XB + (size_t)NTOK * DD * 2;        // 16,843,776 (64 MB)
  const size_t OFF_H   = OFF_W1T + (size_t)EE * DD * HH * 2;    // 83,952,640 (64 MB)
  const size_t OFF_W2T = OFF_XB;                      // overlay; tr2 runs after gemm1
  const size_t NEED    = OFF_H + (size_t)NTOK * HH * 2;         // 151,061,504

  k_router<<<NTOK / 4, 256, 0, stream>>>(x, Wr, br, probs, idxf, idxi);
  k_compact<<<1, 512, 0, stream>>>(idxi, cnt, off, sorted, meta);

  if (ws_size >= NEED) {
    unsigned short* xb  = (unsigned short*)(ws + OFF_XB);
    unsigned short* W1t = (unsigned short*)(ws + OFF_W1T);
    unsigned short* W2t = (unsigned short*)(ws + OFF_W2T);
    unsigned short* h   = (unsigned short*)(ws + OFF_H);
    k_cvt_x<<<(NTOK * DD) / (256 * 8), 256, 0, stream>>>(x, xb);
    k_trcvt<<<dim3(HH / 32, DD / 32, EE), 256, 0, stream>>>(W1, W1t, DD, HH);
    k_gemm1n<<<dim3(MAXBLK, HH / 128), 256, 0, stream>>>(xb, W1t, b1, meta, cnt, off, sorted, h);
    k_trcvt<<<dim3(DD / 32, HH / 32, EE), 256, 0, stream>>>(W2, W2t, HH, DD);
    k_gemm2n<<<dim3(MAXBLK, DD / 128), 256, 0, stream>>>(h, W2t, b2, meta, cnt, off, sorted, out);
  } else {
    unsigned short* h = (unsigned short*)(ws + OFF_XB);
    k_gemm1_f32<<<dim3(EE * (NTOK / BM), HH / BN), 256, 0, stream>>>(x, W1, b1, cnt, off, sorted, h);
    k_gemm2_f32<<<dim3(EE * (NTOK / BM), DD / BN), 256, 0, stream>>>(h, W2, b2, cnt, off, sorted, out);
  }
}